// Round 4
// baseline (481.499 us; speedup 1.0000x reference)
//
#include <hip/hip_runtime.h>
#include <math.h>

// HairBundle SDE drift+diffusion, fp32, B=8,000,000 rows x 5 vars.
// out = drift[B,5] flat ++ diffusion[B,5] flat.
//
// R3: element-per-thread, no LDS, no barriers. Thread j computes out[j] and
// out[B*5+j]. Stores are perfectly coalesced dwords. Loads: x[j] is perfectly
// coalesced; the row-head loads x[5r..5r+2] hit ~13 distinct rows per wave
// per instruction (same-line lanes merge in the TA). Row values are reused by
// 5 threads -> cached loads (no nt); stores are streaming -> nt.

#define THREADS 256

__global__ __launch_bounds__(THREADS) void hb_sde_kernel(
    const float* __restrict__ t,
    const float* __restrict__ x,
    float* __restrict__ drift,
    float* __restrict__ diff,
    unsigned n)   // = B*5 = 40,000,000
{
    const unsigned j = blockIdx.x * THREADS + threadIdx.x;
    if (j >= n) return;

    // wave-uniform sinusoidal drive
    const float force = 0.5f * sinf(6.283185307179586f * t[0]);

    const unsigned r = j / 5u;          // compiler emits magic-mul
    const unsigned v = j - r * 5u;      // which of the 5 vars this thread owns
    const unsigned b = r * 5u;

    const float x_hb = x[b + 0];
    const float x_a  = x[b + 1];
    const float p_m  = x[b + 2];
    const float p_v  = x[j];            // the owned variable's value

    // p_o = sigmoid((x_hb - x_a)/DELTA), DELTA = 0.25
    const float p_o  = 1.0f / (1.0f + __expf(-4.0f * (x_hb - x_a)));
    // f_gs = K_GS*(x_hb - x_a - D_GATE*p_o)
    const float f_gs = 0.75f * (x_hb - x_a - 0.5f * p_o);

    const float d0 = -f_gs - 0.6f * x_hb + force;
    const float d1 = 0.1f * (f_gs - 0.45f * x_a - 0.35f * (1.0f - 0.9f * p_m));
    // v >= 2: a*p_o*(1-p) - k*p  with (a,k) per Ca site
    const float a  = (v == 2) ? 1.2f : ((v == 3) ? 0.7f : 0.3f);
    const float k  = (v == 2) ? 0.8f : ((v == 3) ? 0.5f : 0.4f);
    const float d2 = a * p_o * (1.0f - p_v) - k * p_v;

    const float d = (v == 0) ? d0 : ((v == 1) ? d1 : d2);
    __builtin_nontemporal_store(d, &drift[j]);

    const float g = (v == 0) ? 0.05f : ((v == 1) ? 0.02f : 0.0f);
    __builtin_nontemporal_store(g, &diff[j]);
}

extern "C" void kernel_launch(void* const* d_in, const int* in_sizes, int n_in,
                              void* d_out, int out_size, void* d_ws, size_t ws_size,
                              hipStream_t stream) {
    const float* t = (const float*)d_in[0];
    const float* x = (const float*)d_in[1];
    float* out = (float*)d_out;

    const unsigned n = (unsigned)in_sizes[1];           // 40,000,000
    float* drift = out;
    float* diff  = out + (size_t)n;

    const int grid = (int)((n + THREADS - 1) / THREADS); // 156,250 exact
    hb_sde_kernel<<<grid, THREADS, 0, stream>>>(t, x, drift, diff, n);
}